// Round 6
// baseline (240.046 us; speedup 1.0000x reference)
//
#include <hip/hip_runtime.h>
#include <hip/hip_bf16.h>
#include <math.h>

#define B_ 4
#define T_ 2048
#define D_ 128
#define H_ 8
#define BT_ 8192
#define HD_ 1024

typedef __attribute__((ext_vector_type(8))) short bf16x8;
typedef __attribute__((ext_vector_type(4))) float f32x4;
typedef __attribute__((ext_vector_type(16))) float f32x16;

__device__ __forceinline__ short f2bf(float f) {
  union { float f; unsigned u; } v; v.f = f;
  return (short)((v.u + 0x8000u) >> 16);
}

#if __has_builtin(__builtin_amdgcn_exp2f)
#define EXP2F(x) __builtin_amdgcn_exp2f(x)
#else
#define EXP2F(x) exp2f(x)
#endif

#define QSCALE 0.12752040242046492f   // k^-0.5 * log2(e), folded into Q
#define VSCALE 0.29730177875068026f   // k^-0.25, folded into V

// async global->LDS DMA, 16B/lane; LDS dest = wave-uniform base + lane*16
__device__ __forceinline__ void gld16(const short* g, short* l) {
  __builtin_amdgcn_global_load_lds(
      (const __attribute__((address_space(1))) void*)g,
      (__attribute__((address_space(3))) void*)l, 16, 0, 0);
}

__device__ __forceinline__ void wu_transpose_body(
    const float* __restrict__ Wu, short* __restrict__ WuT,
    short* Tt, int kc, int tid)
{
  #pragma unroll 4
  for (int i = tid; i < 4096; i += 256) {
    int kl = i >> 5, n4 = (i & 31) << 2;
    float4 v = *(const float4*)&Wu[(size_t)(kc*128 + kl) * D_ + n4];
    float vv[4] = {v.x, v.y, v.z, v.w};
    #pragma unroll
    for (int j = 0; j < 4; j++) {
      int n = n4 + j;
      Tt[n*128 + (((kl >> 3) ^ (n & 15)) << 3) + (kl & 7)] = f2bf(vv[j]);
    }
  }
  __syncthreads();
  short* dst = WuT + (size_t)kc * 16384;
  #pragma unroll 2
  for (int i = tid; i < 2048; i += 256)
    *(bf16x8*)&dst[i*8] = *(bf16x8*)&Tt[i*8];
}

// ---------------------------------------------------------------------------
// Kernel 0: prep. blocks 0..23: Wq/Wk/Wv -> WT swizzled tile images.
// blocks 24..87: x -> xbf swizzled tile images. blocks 88..95 (only when
// launched with 96 blocks, i.e. ws has room for a standalone WuT): Wu
// transpose -> WuT tile images.
// ---------------------------------------------------------------------------
__global__ __launch_bounds__(256) void prep(
    const float* __restrict__ x, const float* __restrict__ Wq,
    const float* __restrict__ Wk, const float* __restrict__ Wv,
    const float* __restrict__ Wu,
    short* __restrict__ xbf, short* __restrict__ WT, short* __restrict__ WuT)
{
  __shared__ __align__(16) short Tt[128*128];
  const int tid = threadIdx.x;
  const int id = blockIdx.x;
  if (id < 24) {
    const int wsel = id >> 3, nt = id & 7;
    const float* W = (wsel == 0) ? Wq : (wsel == 1) ? Wk : Wv;
    #pragma unroll 4
    for (int i = tid; i < 4096; i += 256) {
      int k = i >> 5, n4 = (i & 31) << 2;
      float4 v = *(const float4*)&W[(size_t)k * HD_ + nt*128 + n4];
      float vv[4] = {v.x, v.y, v.z, v.w};
      #pragma unroll
      for (int j = 0; j < 4; j++) {
        int n = n4 + j;
        Tt[n*128 + (((k >> 3) ^ (n & 15)) << 3) + (k & 7)] = f2bf(vv[j]);
      }
    }
    __syncthreads();
    short* dst = WT + (size_t)id * 16384;
    #pragma unroll 2
    for (int i = tid; i < 2048; i += 256)
      *(bf16x8*)&dst[i*8] = *(bf16x8*)&Tt[i*8];
  } else if (id < 88) {
    const int xb = id - 24;                       // 64 tiles
    const float* xs = x + (size_t)xb * 16384;
    short* dst = xbf + (size_t)xb * 16384;
    #pragma unroll 4
    for (int i = tid; i < 4096; i += 256) {
      float4 v = ((const float4*)xs)[i];
      int row = i >> 5, c = (i & 31) >> 1, half = i & 1;
      short4 p;
      p.x = f2bf(v.x); p.y = f2bf(v.y); p.z = f2bf(v.z); p.w = f2bf(v.w);
      *(short4*)&dst[(row*16 + (c ^ (row & 15)))*8 + half*4] = p;
    }
  } else {
    wu_transpose_body(Wu, WuT, Tt, id - 88, tid);
  }
}

// ---------------------------------------------------------------------------
// Kernel 1: QKV GEMM. grid (64 m, 8 head) = 512 blocks, 2/CU, ONE block-wave.
// x tile staged ONCE per block (A-reuse x3); per-wsel B DMA into Bs, which
// doubles as the epilogue image after MFMA reads complete. Q/K use swapped
// operands (A=W rows) so acc regs span 4 consecutive d -> short4 stores.
// ---------------------------------------------------------------------------
__global__ __launch_bounds__(256, 2) void qkv_proj(
    const short* __restrict__ xbf, const short* __restrict__ WT,
    short* __restrict__ Qw, short* __restrict__ Kw, short* __restrict__ Vw)
{
  __shared__ __align__(16) short As[16384];
  __shared__ __align__(16) short Bs[16384];
  const int tid = threadIdx.x;
  const int w = tid >> 6, lane = tid & 63, quad = lane >> 4, l16 = lane & 15;
  const int m0 = (int)blockIdx.x * 128;
  const int head = (int)blockIdx.y;
  const int so = w*4096 + lane*8;

  {                                               // prologue: A + B(wsel 0)
    const short* asrc = xbf + (size_t)blockIdx.x * 16384;
    const short* bsrc = WT + (size_t)head * 16384;
    #pragma unroll
    for (int cc = 0; cc < 8; cc++) {
      gld16(asrc + so + cc*512, &As[w*4096 + cc*512]);
      gld16(bsrc + so + cc*512, &Bs[w*4096 + cc*512]);
    }
  }

  const int rA0 = (w & 1) * 64, rB0 = (w >> 1) * 64;
  const int b = m0 >> 11, t0g = m0 & 2047;
  const int h = head;

  #pragma unroll 1
  for (int wsel = 0; wsel < 3; wsel++) {
    __syncthreads();                              // B DMA drained at barrier
    // Q/K: A-operand = W rows (d). V: A = x rows (t).
    const short* RA = (wsel <= 1) ? Bs : As;
    const short* RB = (wsel <= 1) ? As : Bs;

    f32x4 acc[4][4];
    #pragma unroll
    for (int a = 0; a < 4; a++)
      #pragma unroll
      for (int bb = 0; bb < 4; bb++) acc[a][bb] = (f32x4){0.f, 0.f, 0.f, 0.f};

    #pragma unroll
    for (int kk = 0; kk < 4; kk++) {
      const int swz = ((kk*4 + quad) ^ l16) << 3;
      bf16x8 af[4], bfv[4];
      #pragma unroll
      for (int ai = 0; ai < 4; ai++) af[ai]  = *(const bf16x8*)&RA[(rA0 + ai*16 + l16)*128 + swz];
      #pragma unroll
      for (int bi = 0; bi < 4; bi++) bfv[bi] = *(const bf16x8*)&RB[(rB0 + bi*16 + l16)*128 + swz];
      #pragma unroll
      for (int ai = 0; ai < 4; ai++)
        #pragma unroll
        for (int bi = 0; bi < 4; bi++)
          acc[ai][bi] = __builtin_amdgcn_mfma_f32_16x16x32_bf16(af[ai], bfv[bi], acc[ai][bi], 0, 0, 0);
    }

    __syncthreads();   // MFMA reads of Bs complete; Bs becomes the image
    if (wsel <= 1) {
      const float sc = wsel ? 1.0f : QSCALE;
      #pragma unroll
      for (int ai = 0; ai < 4; ai++) {
        #pragma unroll
        for (int bi = 0; bi < 4; bi++) {
          const int d0 = rA0 + ai*16 + quad*4;    // 4 consecutive d
          const int t  = rB0 + bi*16 + l16;
          const int tile = t >> 6, tl = t & 63;
          short4 p;
          p.x = f2bf(acc[ai][bi][0] * sc);
          p.y = f2bf(acc[ai][bi][1] * sc);
          p.z = f2bf(acc[ai][bi][2] * sc);
          p.w = f2bf(acc[ai][bi][3] * sc);
          *(short4*)&Bs[tile*8192 + tl*128 + (((d0 >> 3) ^ (tl & 15)) << 3) + (d0 & 7)] = p;
        }
      }
    } else {
      #pragma unroll
      for (int ai = 0; ai < 4; ai++) {
        #pragma unroll
        for (int bi = 0; bi < 4; bi++) {
          const int t0 = rA0 + ai*16 + quad*4;    // 4 consecutive t
          const int d  = rB0 + bi*16 + l16;
          const int tile = t0 >> 6, tl0 = t0 & 63;
          short4 p;
          p.x = f2bf(acc[ai][bi][0] * VSCALE);
          p.y = f2bf(acc[ai][bi][1] * VSCALE);
          p.z = f2bf(acc[ai][bi][2] * VSCALE);
          p.w = f2bf(acc[ai][bi][3] * VSCALE);
          *(short4*)&Bs[tile*8192 + d*64 + (((tl0 >> 3) ^ (d & 7)) << 3) + (tl0 & 7)] = p;
        }
      }
    }
    __syncthreads();                              // image complete

    short* base = ((wsel == 0) ? Qw : (wsel == 1) ? Kw : Vw)
                + (size_t)(b*H_ + h)*262144 + (size_t)t0g*128;
    #pragma unroll 2
    for (int i = tid; i < 2048; i += 256)
      *(bf16x8*)&base[i*8] = *(bf16x8*)&Bs[i*8];

    if (wsel < 2) {
      __syncthreads();                            // copy-out reads done
      const short* bsrc = WT + (size_t)((wsel + 1)*8 + head) * 16384;
      #pragma unroll
      for (int cc = 0; cc < 8; cc++)
        gld16(bsrc + so + cc*512, &Bs[w*4096 + cc*512]);
    }
  }
}

// ---------------------------------------------------------------------------
// Kernel 2: causal flash attention — r9: 32x32x16 MFMA, quadrant waves.
// Lessons: r7 (dbuf) -> DMA latency not the limit; r8 (QBLK=128) -> LDS
// traffic cut helps only if 4 blocks/CU (16 waves) stays. r5 arithmetic:
// ~9.2MB ds_read_b128/CU ~= 45us of its 64us -> LDS-read-BW bound.
// Fix: 32x32 output tiles read 8B of B-operand per output elem (vs 16B
// for 16x16). 4 waves split S 64x64 into quadrants (wr=w>>1, wc=w&1):
// QK^T 8 MFMA/wave (B 8KB), P -> shared 8KB LDS (one extra barrier),
// PV 8 MFMA/wave (P 4KB + V 8KB). 34KB -> 20KB LDS reads/wave/iter at
// SAME grid (1024), SAME 40KB LDS, SAME occupancy. l[16]/lane reduced
// once in epilogue (shfl + Lred in Ps). VGPR ~115 target; spill shows
// as WRITE_SIZE inflation (r6 signature). C/D 32x32 layout: col=lane&31,
// row=(reg&3)+8*(reg>>2)+4*(lane>>5) [m74/m101]; A/B: row/col=lane&31,
// k=8*(lane>>5)+j (confirmed by the working 16x16 pattern here).
// ---------------------------------------------------------------------------
__global__ __launch_bounds__(256, 4) void attn_kernel(
    const short* __restrict__ Qw, const short* __restrict__ Kw,
    const short* __restrict__ Vw, short* __restrict__ attnw)
{
  __shared__ __align__(16) short Ks[8192];        // 64t x 128d swizzled; epi image
  __shared__ __align__(16) short Vs[8192];        // 128d x 64t swizzled
  __shared__ __align__(16) short Ps[4096];        // 64q x 64k swizzled, shared; Lred in epi

  const int tid = threadIdx.x;
  const int id = (int)blockIdx.x;                 // 1024 blocks
  const int xcd = id & 7;
  const int j   = id >> 3;                        // 0..127 within XCD
  const int u   = j & 3;
  const int q   = (j >> 2) & 7;
  const int vv  = (j >> 5) & 3;
  const int slot = u ^ vv;
  const int qi = (slot == 0) ? q : (slot == 1) ? 15 - q
               : (slot == 2) ? 16 + q : 31 - q;
  const int bh = xcd | (u << 3);
  const int b = bh >> 3, h = bh & 7;
  const int w = tid >> 6, lane = tid & 63;
  const int wr = w >> 1, wc = w & 1;
  const int l32 = lane & 31, lhi = lane >> 5;

  const short* Qp = Qw + (size_t)bh * 262144;     // swizzled 16KB tiles
  const short* Kp = Kw + (size_t)bh * 262144;
  const short* Vp = Vw + (size_t)bh * 262144;

  // Q rows 32*wr + l32 of tile qi; 8 k-steps of 16 (k = st*16 + lhi*8 + j)
  bf16x8 qa[8];
  {
    const int tl = wr*32 + l32;
    const short* qp = Qp + ((size_t)qi << 13) + tl*128;
    #pragma unroll
    for (int st = 0; st < 8; st++) {
      const int g = st*2 + lhi;
      qa[st] = *(const bf16x8*)(qp + ((g ^ (tl & 15)) << 3));
    }
  }

  f32x16 o[2];
  o[0] = (f32x16){0,0,0,0,0,0,0,0,0,0,0,0,0,0,0,0};
  o[1] = (f32x16){0,0,0,0,0,0,0,0,0,0,0,0,0,0,0,0};
  float la[16] = {};

  const int so = w*2048 + lane*8;
  const int nIter = qi + 1;
  const int key = wc*32 + l32;                    // this lane's S column

  for (int it = 0; it < nIter; ++it) {
    if (it) __syncthreads();                      // prev PV done w/ Vs & Ps
    {
      const short* kt = Kp + ((size_t)it << 13);
      const short* vt = Vp + ((size_t)it << 13);
      #pragma unroll
      for (int cc = 0; cc < 4; cc++) {
        gld16(kt + so + cc*512, &Ks[w*2048 + cc*512]);
        gld16(vt + so + cc*512, &Vs[w*2048 + cc*512]);
      }
    }
    __syncthreads();                              // DMA drained at barrier

    // QK^T: S quadrant [32wr..][32wc..], 8 k-steps of 16 over d
    f32x16 s = (f32x16){0,0,0,0,0,0,0,0,0,0,0,0,0,0,0,0};
    __builtin_amdgcn_s_setprio(1);
    #pragma unroll
    for (int st = 0; st < 8; st++) {
      const int g = st*2 + lhi;
      bf16x8 kb = *(const bf16x8*)&Ks[key*128 + ((g ^ (key & 15)) << 3)];
      s = __builtin_amdgcn_mfma_f32_32x32x16_bf16(qa[st], kb, s, 0, 0, 0);
    }
    __builtin_amdgcn_s_setprio(0);

    // softmax piece: exp2, accumulate l, write P quadrant (shared)
    if (it < qi) {                                // unmasked tile
      #pragma unroll
      for (int r = 0; r < 16; r++) {
        const int rl = (r & 3) + ((r >> 2) << 3) + (lhi << 2);
        const int row = wr*32 + rl;
        float p = EXP2F(s[r]);
        la[r] += p;
        Ps[row*64 + ((((key >> 3) ^ (row & 7)) << 3)) + (key & 7)] = f2bf(p);
      }
    } else {                                      // diagonal tile: mask
      #pragma unroll
      for (int r = 0; r < 16; r++) {
        const int rl = (r & 3) + ((r >> 2) << 3) + (lhi << 2);
        const int row = wr*32 + rl;
        float p = (key > row) ? 0.f : EXP2F(s[r]);
        la[r] += p;
        Ps[row*64 + ((((key >> 3) ^ (row & 7)) << 3)) + (key & 7)] = f2bf(p);
      }
    }
    __syncthreads();                              // P tile complete

    // PV: O[32wr rows][64wc + 0..63 cols], 4 k-steps of 16 over keys
    __builtin_amdgcn_s_setprio(1);
    #pragma unroll
    for (int st = 0; st < 4; st++) {
      const int prow = wr*32 + l32;
      const int kg = st*2 + lhi;                  // key>>3
      bf16x8 pa = *(const bf16x8*)&Ps[prow*64 + ((kg ^ (prow & 7)) << 3)];
      #pragma unroll
      for (int dt = 0; dt < 2; dt++) {
        const int d = wc*64 + dt*32 + l32;
        bf16x8 vb = *(const bf16x8*)&Vs[d*64 + ((kg ^ (d & 7)) << 3)];
        o[dt] = __builtin_amdgcn_mfma_f32_32x32x16_bf16(pa, vb, o[dt], 0, 0, 0);
      }
    }
    __builtin_amdgcn_s_setprio(0);
  }

  // epilogue: reduce la over 32 cols (lane bits 0..4), combine wc halves
  #pragma unroll
  for (int r = 0; r < 16; r++) {
    float t = la[r];
    t += __shfl_xor(t, 1); t += __shfl_xor(t, 2); t += __shfl_xor(t, 4);
    t += __shfl_xor(t, 8); t += __shfl_xor(t, 16);
    la[r] = t;
  }
  __syncthreads();                                // all PV reads of Ps done
  float* Lr = (float*)Ps;                         // [2][64] row-sum halves
  if (l32 == 0) {
    #pragma unroll
    for (int r = 0; r < 16; r++) {
      const int rl = (r & 3) + ((r >> 2) << 3) + (lhi << 2);
      Lr[wc*64 + wr*32 + rl] = la[r];
    }
  }
  __syncthreads();
  // normalize + build 64x128 image in Ks
  #pragma unroll
  for (int r = 0; r < 16; r++) {
    const int rl = (r & 3) + ((r >> 2) << 3) + (lhi << 2);
    const int row = wr*32 + rl;
    const float inv = 1.0f / (Lr[row] + Lr[64 + row]);
    #pragma unroll
    for (int dt = 0; dt < 2; dt++) {
      const int col = wc*64 + dt*32 + l32;
      const int sub = row >> 5, r32 = row & 31, c = col >> 3;
      Ks[sub*4096 + r32*128 + ((c ^ (r32 & 15)) << 3) + (col & 7)] =
          f2bf(o[dt][r] * inv);
    }
  }
  __syncthreads();
  const int st0 = b*64 + qi*2;
  #pragma unroll 2
  for (int i = tid; i < 1024; i += 256) {
    const int sub = i >> 9, rem = i & 511;
    short* dst = attnw + ((size_t)(st0 + sub)*8 + h)*4096 + rem*8;
    *(bf16x8*)dst = *(const bf16x8*)&Ks[i*8];
  }
}

// ---------------------------------------------------------------------------
// Kernel 3 (fallback only): Wu -> WuT tile images into dead Kw, after attn.
// ---------------------------------------------------------------------------
__global__ __launch_bounds__(256) void wu_prep(
    const float* __restrict__ Wu, short* __restrict__ WuT)
{
  __shared__ __align__(16) short Tt[128*128];
  wu_transpose_body(Wu, WuT, Tt, blockIdx.x, threadIdx.x);
}

// ---------------------------------------------------------------------------
// Kernel 4: out = attn @ Wu + bu -> fp32. DMA-staged, double-buffered over
// 8 k-chunks, fused bias. grid 512 (m-tile 16), 2 blocks/CU.
// ---------------------------------------------------------------------------
__global__ __launch_bounds__(256, 2) void out_proj(
    const short* __restrict__ attnw, const short* __restrict__ WuT,
    const float* __restrict__ bu, float* __restrict__ out)
{
  __shared__ __align__(16) short As2[2][2048];
  __shared__ __align__(16) short Bs2[2][16384];
  const int tid = threadIdx.x;
  const int w = tid >> 6, lane = tid & 63, quad = lane >> 4, l16 = lane & 15;
  const int m0 = (int)blockIdx.x * 16;
  const int mtile32 = m0 >> 5, half = (m0 >> 4) & 1;

  f32x4 o2[2];
  o2[0] = (f32x4){0,0,0,0}; o2[1] = (f32x4){0,0,0,0};

  {
    const short* ab = attnw + (size_t)(mtile32*8)*4096 + half*2048;
    gld16(ab + w*512 + lane*8, &As2[0][w*512]);
    #pragma unroll
    for (int cc = 0; cc < 8; cc++)
      gld16(WuT + w*4096 + cc*512 + lane*8, &Bs2[0][w*4096 + cc*512]);
  }
  int buf = 0;

  for (int kc = 0; kc < 8; kc++) {
    __syncthreads();
    if (kc < 7) {
      const short* ab = attnw + (size_t)(mtile32*8 + kc + 1)*4096 + half*2048;
      const short* bb = WuT + (size_t)(kc + 1)*16384;
      gld16(ab + w*512 + lane*8, &As2[buf^1][w*512]);
      #pragma unroll
      for (int cc = 0; cc < 8; cc++)
        gld16(bb + w*4096 + cc*512 + lane*8, &Bs2[buf^1][w*4096 + cc*512]);
    }
    const short* as = &As2[buf][0];
    const short* bs = &Bs2[buf][0];
    #pragma unroll
    for (int kk = 0; kk < 4; kk++) {
      const int swz = ((kk*4 + quad) ^ l16) << 3;
      bf16x8 a = *(const bf16x8*)&as[l16*128 + swz];
      #pragma unroll
      for (int e = 0; e < 2; e++) {
        bf16x8 bfr = *(const bf16x8*)&bs[((w*2 + e)*16 + l16)*128 + swz];
        o2[e] = __builtin_amdgcn_mfma_f32_16x16x32_bf16(a, bfr, o2[e], 0, 0, 0);
      }
    }
    buf ^= 1;
  }

  #pragma unroll
  for (int e = 0; e < 2; e++) {
    const int n = (w*2 + e)*16 + l16;
    const float bias = bu[n];
    #pragma unroll
    for (int r = 0; r < 4; r++) {
      const int mm = m0 + quad*4 + r;
      out[(size_t)mm*D_ + n] = o2[e][r] + bias;
    }
  }
}

extern "C" void kernel_launch(void* const* d_in, const int* in_sizes, int n_in,
                              void* d_out, int out_size, void* d_ws, size_t ws_size,
                              hipStream_t stream) {
  (void)in_sizes; (void)n_in; (void)out_size;
  const float* x  = (const float*)d_in[0];
  const float* Wq = (const float*)d_in[1];
  const float* Wk = (const float*)d_in[2];
  const float* Wv = (const float*)d_in[3];
  const float* Wu = (const float*)d_in[4];
  const float* bu = (const float*)d_in[5];
  float* out = (float*)d_out;

  const size_t headElems = (size_t)B_ * H_ * T_ * D_;   // 8,388,608
  short* Qw    = (short*)d_ws;
  short* Kw    = Qw + headElems;
  short* Vw    = Kw + headElems;
  short* attnw = Vw + headElems;                        // 16 MB (tiled images)
  short* xbf = attnw;                                   // prep outputs live in
  short* WT  = attnw + 1048576;                         // not-yet-written attnw

  // WuT: own region past the 64 MB map if ws allows (prep fills it, no
  // wu_prep launch); else dead-Kw reuse after attn (extra launch).
  const bool extraWu = ws_size >= (64ull << 20) + (1ull << 20);
  short* WuT = extraWu ? (short*)((char*)d_ws + (64ull << 20)) : Kw;

  prep<<<dim3(extraWu ? 96 : 88), 256, 0, stream>>>(x, Wq, Wk, Wv, Wu, xbf, WT, WuT);
  qkv_proj<<<dim3(64, 8), 256, 0, stream>>>(xbf, WT, Qw, Kw, Vw);
  attn_kernel<<<dim3(1024), 256, 0, stream>>>(Qw, Kw, Vw, attnw);
  if (!extraWu) wu_prep<<<dim3(8), 256, 0, stream>>>(Wu, WuT);
  out_proj<<<dim3(512), 256, 0, stream>>>(attnw, WuT, bu, out);
}

// Round 7
// 152.523 us; speedup vs baseline: 1.5738x; 1.5738x over previous
//
#include <hip/hip_runtime.h>
#include <hip/hip_bf16.h>
#include <math.h>

#define B_ 4
#define T_ 2048
#define D_ 128
#define H_ 8
#define BT_ 8192
#define HD_ 1024

typedef __attribute__((ext_vector_type(8))) short bf16x8;
typedef __attribute__((ext_vector_type(4))) float f32x4;

__device__ __forceinline__ short f2bf(float f) {
  union { float f; unsigned u; } v; v.f = f;
  return (short)((v.u + 0x8000u) >> 16);
}

#if __has_builtin(__builtin_amdgcn_exp2f)
#define EXP2F(x) __builtin_amdgcn_exp2f(x)
#else
#define EXP2F(x) exp2f(x)
#endif

#define QSCALE 0.12752040242046492f   // k^-0.5 * log2(e), folded into Q
#define VSCALE 0.29730177875068026f   // k^-0.25, folded into V

// async global->LDS DMA, 16B/lane; LDS dest = wave-uniform base + lane*16
__device__ __forceinline__ void gld16(const short* g, short* l) {
  __builtin_amdgcn_global_load_lds(
      (const __attribute__((address_space(1))) void*)g,
      (__attribute__((address_space(3))) void*)l, 16, 0, 0);
}

__device__ __forceinline__ void wu_transpose_body(
    const float* __restrict__ Wu, short* __restrict__ WuT,
    short* Tt, int kc, int tid)
{
  #pragma unroll 4
  for (int i = tid; i < 4096; i += 256) {
    int kl = i >> 5, n4 = (i & 31) << 2;
    float4 v = *(const float4*)&Wu[(size_t)(kc*128 + kl) * D_ + n4];
    float vv[4] = {v.x, v.y, v.z, v.w};
    #pragma unroll
    for (int j = 0; j < 4; j++) {
      int n = n4 + j;
      Tt[n*128 + (((kl >> 3) ^ (n & 15)) << 3) + (kl & 7)] = f2bf(vv[j]);
    }
  }
  __syncthreads();
  short* dst = WuT + (size_t)kc * 16384;
  #pragma unroll 2
  for (int i = tid; i < 2048; i += 256)
    *(bf16x8*)&dst[i*8] = *(bf16x8*)&Tt[i*8];
}

// ---------------------------------------------------------------------------
// Kernel 0: prep. blocks 0..23: Wq/Wk/Wv -> WT swizzled tile images.
// blocks 24..87: x -> xbf swizzled tile images. blocks 88..95 (only when
// launched with 96 blocks, i.e. ws has room for a standalone WuT): Wu
// transpose -> WuT tile images.
// ---------------------------------------------------------------------------
__global__ __launch_bounds__(256) void prep(
    const float* __restrict__ x, const float* __restrict__ Wq,
    const float* __restrict__ Wk, const float* __restrict__ Wv,
    const float* __restrict__ Wu,
    short* __restrict__ xbf, short* __restrict__ WT, short* __restrict__ WuT)
{
  __shared__ __align__(16) short Tt[128*128];
  const int tid = threadIdx.x;
  const int id = blockIdx.x;
  if (id < 24) {
    const int wsel = id >> 3, nt = id & 7;
    const float* W = (wsel == 0) ? Wq : (wsel == 1) ? Wk : Wv;
    #pragma unroll 4
    for (int i = tid; i < 4096; i += 256) {
      int k = i >> 5, n4 = (i & 31) << 2;
      float4 v = *(const float4*)&W[(size_t)k * HD_ + nt*128 + n4];
      float vv[4] = {v.x, v.y, v.z, v.w};
      #pragma unroll
      for (int j = 0; j < 4; j++) {
        int n = n4 + j;
        Tt[n*128 + (((k >> 3) ^ (n & 15)) << 3) + (k & 7)] = f2bf(vv[j]);
      }
    }
    __syncthreads();
    short* dst = WT + (size_t)id * 16384;
    #pragma unroll 2
    for (int i = tid; i < 2048; i += 256)
      *(bf16x8*)&dst[i*8] = *(bf16x8*)&Tt[i*8];
  } else if (id < 88) {
    const int xb = id - 24;                       // 64 tiles
    const float* xs = x + (size_t)xb * 16384;
    short* dst = xbf + (size_t)xb * 16384;
    #pragma unroll 4
    for (int i = tid; i < 4096; i += 256) {
      float4 v = ((const float4*)xs)[i];
      int row = i >> 5, c = (i & 31) >> 1, half = i & 1;
      short4 p;
      p.x = f2bf(v.x); p.y = f2bf(v.y); p.z = f2bf(v.z); p.w = f2bf(v.w);
      *(short4*)&dst[(row*16 + (c ^ (row & 15)))*8 + half*4] = p;
    }
  } else {
    wu_transpose_body(Wu, WuT, Tt, id - 88, tid);
  }
}

// ---------------------------------------------------------------------------
// Kernel 1: QKV GEMM. grid (64 m, 8 head) = 512 blocks, 2/CU, ONE block-wave.
// x tile staged ONCE per block (A-reuse x3); per-wsel B DMA into Bs, which
// doubles as the epilogue image after MFMA reads complete. Q/K use swapped
// operands (A=W rows) so acc regs span 4 consecutive d -> short4 stores.
// ---------------------------------------------------------------------------
__global__ __launch_bounds__(256, 2) void qkv_proj(
    const short* __restrict__ xbf, const short* __restrict__ WT,
    short* __restrict__ Qw, short* __restrict__ Kw, short* __restrict__ Vw)
{
  __shared__ __align__(16) short As[16384];
  __shared__ __align__(16) short Bs[16384];
  const int tid = threadIdx.x;
  const int w = tid >> 6, lane = tid & 63, quad = lane >> 4, l16 = lane & 15;
  const int m0 = (int)blockIdx.x * 128;
  const int head = (int)blockIdx.y;
  const int so = w*4096 + lane*8;

  {                                               // prologue: A + B(wsel 0)
    const short* asrc = xbf + (size_t)blockIdx.x * 16384;
    const short* bsrc = WT + (size_t)head * 16384;
    #pragma unroll
    for (int cc = 0; cc < 8; cc++) {
      gld16(asrc + so + cc*512, &As[w*4096 + cc*512]);
      gld16(bsrc + so + cc*512, &Bs[w*4096 + cc*512]);
    }
  }

  const int rA0 = (w & 1) * 64, rB0 = (w >> 1) * 64;
  const int b = m0 >> 11, t0g = m0 & 2047;
  const int h = head;

  #pragma unroll 1
  for (int wsel = 0; wsel < 3; wsel++) {
    __syncthreads();                              // B DMA drained at barrier
    // Q/K: A-operand = W rows (d). V: A = x rows (t).
    const short* RA = (wsel <= 1) ? Bs : As;
    const short* RB = (wsel <= 1) ? As : Bs;

    f32x4 acc[4][4];
    #pragma unroll
    for (int a = 0; a < 4; a++)
      #pragma unroll
      for (int bb = 0; bb < 4; bb++) acc[a][bb] = (f32x4){0.f, 0.f, 0.f, 0.f};

    #pragma unroll
    for (int kk = 0; kk < 4; kk++) {
      const int swz = ((kk*4 + quad) ^ l16) << 3;
      bf16x8 af[4], bfv[4];
      #pragma unroll
      for (int ai = 0; ai < 4; ai++) af[ai]  = *(const bf16x8*)&RA[(rA0 + ai*16 + l16)*128 + swz];
      #pragma unroll
      for (int bi = 0; bi < 4; bi++) bfv[bi] = *(const bf16x8*)&RB[(rB0 + bi*16 + l16)*128 + swz];
      #pragma unroll
      for (int ai = 0; ai < 4; ai++)
        #pragma unroll
        for (int bi = 0; bi < 4; bi++)
          acc[ai][bi] = __builtin_amdgcn_mfma_f32_16x16x32_bf16(af[ai], bfv[bi], acc[ai][bi], 0, 0, 0);
    }

    __syncthreads();   // MFMA reads of Bs complete; Bs becomes the image
    if (wsel <= 1) {
      const float sc = wsel ? 1.0f : QSCALE;
      #pragma unroll
      for (int ai = 0; ai < 4; ai++) {
        #pragma unroll
        for (int bi = 0; bi < 4; bi++) {
          const int d0 = rA0 + ai*16 + quad*4;    // 4 consecutive d
          const int t  = rB0 + bi*16 + l16;
          const int tile = t >> 6, tl = t & 63;
          short4 p;
          p.x = f2bf(acc[ai][bi][0] * sc);
          p.y = f2bf(acc[ai][bi][1] * sc);
          p.z = f2bf(acc[ai][bi][2] * sc);
          p.w = f2bf(acc[ai][bi][3] * sc);
          *(short4*)&Bs[tile*8192 + tl*128 + (((d0 >> 3) ^ (tl & 15)) << 3) + (d0 & 7)] = p;
        }
      }
    } else {
      #pragma unroll
      for (int ai = 0; ai < 4; ai++) {
        #pragma unroll
        for (int bi = 0; bi < 4; bi++) {
          const int t0 = rA0 + ai*16 + quad*4;    // 4 consecutive t
          const int d  = rB0 + bi*16 + l16;
          const int tile = t0 >> 6, tl0 = t0 & 63;
          short4 p;
          p.x = f2bf(acc[ai][bi][0] * VSCALE);
          p.y = f2bf(acc[ai][bi][1] * VSCALE);
          p.z = f2bf(acc[ai][bi][2] * VSCALE);
          p.w = f2bf(acc[ai][bi][3] * VSCALE);
          *(short4*)&Bs[tile*8192 + d*64 + (((tl0 >> 3) ^ (d & 7)) << 3) + (tl0 & 7)] = p;
        }
      }
    }
    __syncthreads();                              // image complete

    short* base = ((wsel == 0) ? Qw : (wsel == 1) ? Kw : Vw)
                + (size_t)(b*H_ + h)*262144 + (size_t)t0g*128;
    #pragma unroll 2
    for (int i = tid; i < 2048; i += 256)
      *(bf16x8*)&base[i*8] = *(bf16x8*)&Bs[i*8];

    if (wsel < 2) {
      __syncthreads();                            // copy-out reads done
      const short* bsrc = WT + (size_t)((wsel + 1)*8 + head) * 16384;
      #pragma unroll
      for (int cc = 0; cc < 8; cc++)
        gld16(bsrc + so + cc*512, &Bs[w*4096 + cc*512]);
    }
  }
}

// ---------------------------------------------------------------------------
// Kernel 2: causal flash attention — r10: r5 structure + scheduling only.
// After r6(spill)/r7(dbuf neutral-)/r8(occupancy)/r9(32x32 spill+conflict):
// r5's 16x16 single-buffer 4-block/CU layout is the structural optimum.
// Two zero-structure levers: (1) T5 setprio around MFMA clusters (m191:
// +4-7% attn when co-resident blocks are at independent phases — exactly
// this kernel). (2) T4 counted vmcnt: issue 4 K-loads then 4 V-loads;
// vmcnt(4)+barrier lets QK start while V DMA is in flight; V drains at the
// pre-softmax __syncthreads(). sched_barrier(0) fences the asm per rule 18.
// ---------------------------------------------------------------------------
__global__ __launch_bounds__(256, 4) void attn_kernel(
    const short* __restrict__ Qw, const short* __restrict__ Kw,
    const short* __restrict__ Vw, short* __restrict__ attnw)
{
  __shared__ __align__(16) short Ks[8192];        // 64t x 128d swizzled
  __shared__ __align__(16) short Vs[8192];        // 128d x 64t swizzled
  __shared__ __align__(16) short Ps[4096];        // 4 waves x 16x64

  const int tid = threadIdx.x;
  const int id = (int)blockIdx.x;                 // 1024 blocks
  const int xcd = id & 7;
  const int j   = id >> 3;                        // 0..127 within XCD
  const int u   = j & 3;
  const int q   = (j >> 2) & 7;
  const int vv  = (j >> 5) & 3;
  const int slot = u ^ vv;
  const int qi = (slot == 0) ? q : (slot == 1) ? 15 - q
               : (slot == 2) ? 16 + q : 31 - q;
  const int bh = xcd | (u << 3);
  const int b = bh >> 3, h = bh & 7;
  const int w = tid >> 6, lane = tid & 63, quad = lane >> 4, l16 = lane & 15;
  const int rowQ = qi*64 + w*16;

  const short* Qp = Qw + (size_t)bh * 262144;     // swizzled 16KB tiles
  const short* Kp = Kw + (size_t)bh * 262144;
  const short* Vp = Vw + (size_t)bh * 262144;

  bf16x8 qa[4];
  {
    const int tl = (rowQ & 63) + l16;
    const short* qp = Qp + ((size_t)(rowQ >> 6) << 13) + tl*128;
    #pragma unroll
    for (int kk = 0; kk < 4; kk++)
      qa[kk] = *(const bf16x8*)(qp + (((kk*4 + quad) ^ (tl & 15)) << 3));
  }

  f32x4 o[8];
  #pragma unroll
  for (int e = 0; e < 8; e++) o[e] = (f32x4){0,0,0,0};
  float l[4] = {0,0,0,0};

  short* Pw = &Ps[w*1024];
  const int so = w*2048 + lane*8;
  const int nIter = qi + 1;

  for (int it = 0; it < nIter; ++it) {
    if (it) __syncthreads();                      // A: prev consumers done
    {
      const short* kt = Kp + ((size_t)it << 13);
      const short* vt = Vp + ((size_t)it << 13);
      #pragma unroll
      for (int cc = 0; cc < 4; cc++)              // K first...
        gld16(kt + so + cc*512, &Ks[w*2048 + cc*512]);
      #pragma unroll
      for (int cc = 0; cc < 4; cc++)              // ...then V
        gld16(vt + so + cc*512, &Vs[w*2048 + cc*512]);
    }
    // T4: wait only the 4 K loads (issue-ordered); V stays in flight.
    asm volatile("s_waitcnt vmcnt(4)" ::: "memory");
    __builtin_amdgcn_sched_barrier(0);
    __builtin_amdgcn_s_barrier();                 // B: K ready block-wide
    __builtin_amdgcn_sched_barrier(0);

    f32x4 s[4];
    #pragma unroll
    for (int nj = 0; nj < 4; nj++) s[nj] = (f32x4){0,0,0,0};
    __builtin_amdgcn_s_setprio(1);
    #pragma unroll
    for (int kk = 0; kk < 4; kk++) {
      const int swz = ((kk*4 + quad) ^ l16) << 3;
      #pragma unroll
      for (int nj = 0; nj < 4; nj++) {
        bf16x8 kb = *(const bf16x8*)&Ks[(nj*16 + l16)*128 + swz];
        s[nj] = __builtin_amdgcn_mfma_f32_16x16x32_bf16(qa[kk], kb, s[nj], 0, 0, 0);
      }
    }
    __builtin_amdgcn_s_setprio(0);

    __syncthreads();                              // C: V drained (vmcnt 0)

    if (it < qi) {                                // unmasked tile
      #pragma unroll
      for (int nj = 0; nj < 4; nj++) {
        #pragma unroll
        for (int r = 0; r < 4; r++) {
          float p = EXP2F(s[nj][r]);
          l[r] += p;
          const int row = quad*4 + r, col = nj*16 + l16;
          Pw[row*64 + (((col >> 3) ^ (row & 7)) << 3) + (col & 7)] = f2bf(p);
        }
      }
    } else {                                      // diagonal tile: mask
      const int s0 = it * 64;
      #pragma unroll
      for (int nj = 0; nj < 4; nj++) {
        const int key = s0 + nj*16 + l16;
        #pragma unroll
        for (int r = 0; r < 4; r++) {
          float p = (key > rowQ + quad*4 + r) ? 0.f : EXP2F(s[nj][r]);
          l[r] += p;
          const int row = quad*4 + r, col = nj*16 + l16;
          Pw[row*64 + (((col >> 3) ^ (row & 7)) << 3) + (col & 7)] = f2bf(p);
        }
      }
    }

    __builtin_amdgcn_s_setprio(1);
    #pragma unroll
    for (int kk2 = 0; kk2 < 2; kk2++) {
      const int swz = ((kk2*4 + quad) ^ (l16 & 7)) << 3;
      bf16x8 pa = *(bf16x8*)&Pw[l16*64 + swz];
      #pragma unroll
      for (int e = 0; e < 8; e++) {
        bf16x8 vb = *(const bf16x8*)&Vs[(e*16 + l16)*64 + swz];
        o[e] = __builtin_amdgcn_mfma_f32_16x16x32_bf16(pa, vb, o[e], 0, 0, 0);
      }
    }
    __builtin_amdgcn_s_setprio(0);
  }

  // epilogue: l-reduce, build 64x128 LDS image in Ks, b128 copy-out
  #pragma unroll
  for (int r = 0; r < 4; r++) {
    float t = l[r];
    t += __shfl_xor(t, 1); t += __shfl_xor(t, 2);
    t += __shfl_xor(t, 4); t += __shfl_xor(t, 8);
    l[r] = 1.0f / t;
  }
  __syncthreads();                                // done reading Ks/Vs
  #pragma unroll
  for (int e = 0; e < 8; e++) {
    const int c = e*2 + (l16 >> 3);
    #pragma unroll
    for (int r = 0; r < 4; r++) {
      const int lrow = w*16 + quad*4 + r;         // 0..63
      const int sub = lrow >> 5, r32 = lrow & 31;
      Ks[sub*4096 + r32*128 + ((c ^ (r32 & 15)) << 3) + (l16 & 7)] =
          f2bf(o[e][r] * l[r]);
    }
  }
  __syncthreads();
  const int st0 = b*64 + qi*2;
  #pragma unroll 2
  for (int i = tid; i < 1024; i += 256) {
    const int sub = i >> 9, rem = i & 511;
    short* dst = attnw + ((size_t)(st0 + sub)*8 + h)*4096 + rem*8;
    *(bf16x8*)dst = *(const bf16x8*)&Ks[i*8];
  }
}

// ---------------------------------------------------------------------------
// Kernel 3 (fallback only): Wu -> WuT tile images into dead Kw, after attn.
// ---------------------------------------------------------------------------
__global__ __launch_bounds__(256) void wu_prep(
    const float* __restrict__ Wu, short* __restrict__ WuT)
{
  __shared__ __align__(16) short Tt[128*128];
  wu_transpose_body(Wu, WuT, Tt, blockIdx.x, threadIdx.x);
}

// ---------------------------------------------------------------------------
// Kernel 4: out = attn @ Wu + bu -> fp32. DMA-staged, double-buffered over
// 8 k-chunks, fused bias. grid 512 (m-tile 16), 2 blocks/CU.
// ---------------------------------------------------------------------------
__global__ __launch_bounds__(256, 2) void out_proj(
    const short* __restrict__ attnw, const short* __restrict__ WuT,
    const float* __restrict__ bu, float* __restrict__ out)
{
  __shared__ __align__(16) short As2[2][2048];
  __shared__ __align__(16) short Bs2[2][16384];
  const int tid = threadIdx.x;
  const int w = tid >> 6, lane = tid & 63, quad = lane >> 4, l16 = lane & 15;
  const int m0 = (int)blockIdx.x * 16;
  const int mtile32 = m0 >> 5, half = (m0 >> 4) & 1;

  f32x4 o2[2];
  o2[0] = (f32x4){0,0,0,0}; o2[1] = (f32x4){0,0,0,0};

  {
    const short* ab = attnw + (size_t)(mtile32*8)*4096 + half*2048;
    gld16(ab + w*512 + lane*8, &As2[0][w*512]);
    #pragma unroll
    for (int cc = 0; cc < 8; cc++)
      gld16(WuT + w*4096 + cc*512 + lane*8, &Bs2[0][w*4096 + cc*512]);
  }
  int buf = 0;

  for (int kc = 0; kc < 8; kc++) {
    __syncthreads();
    if (kc < 7) {
      const short* ab = attnw + (size_t)(mtile32*8 + kc + 1)*4096 + half*2048;
      const short* bb = WuT + (size_t)(kc + 1)*16384;
      gld16(ab + w*512 + lane*8, &As2[buf^1][w*512]);
      #pragma unroll
      for (int cc = 0; cc < 8; cc++)
        gld16(bb + w*4096 + cc*512 + lane*8, &Bs2[buf^1][w*4096 + cc*512]);
    }
    const short* as = &As2[buf][0];
    const short* bs = &Bs2[buf][0];
    #pragma unroll
    for (int kk = 0; kk < 4; kk++) {
      const int swz = ((kk*4 + quad) ^ l16) << 3;
      bf16x8 a = *(const bf16x8*)&as[l16*128 + swz];
      #pragma unroll
      for (int e = 0; e < 2; e++) {
        bf16x8 bfr = *(const bf16x8*)&bs[((w*2 + e)*16 + l16)*128 + swz];
        o2[e] = __builtin_amdgcn_mfma_f32_16x16x32_bf16(a, bfr, o2[e], 0, 0, 0);
      }
    }
    buf ^= 1;
  }

  #pragma unroll
  for (int e = 0; e < 2; e++) {
    const int n = (w*2 + e)*16 + l16;
    const float bias = bu[n];
    #pragma unroll
    for (int r = 0; r < 4; r++) {
      const int mm = m0 + quad*4 + r;
      out[(size_t)mm*D_ + n] = o2[e][r] + bias;
    }
  }
}

extern "C" void kernel_launch(void* const* d_in, const int* in_sizes, int n_in,
                              void* d_out, int out_size, void* d_ws, size_t ws_size,
                              hipStream_t stream) {
  (void)in_sizes; (void)n_in; (void)out_size;
  const float* x  = (const float*)d_in[0];
  const float* Wq = (const float*)d_in[1];
  const float* Wk = (const float*)d_in[2];
  const float* Wv = (const float*)d_in[3];
  const float* Wu = (const float*)d_in[4];
  const float* bu = (const float*)d_in[5];
  float* out = (float*)d_out;

  const size_t headElems = (size_t)B_ * H_ * T_ * D_;   // 8,388,608
  short* Qw    = (short*)d_ws;
  short* Kw    = Qw + headElems;
  short* Vw    = Kw + headElems;
  short* attnw = Vw + headElems;                        // 16 MB (tiled images)
  short* xbf = attnw;                                   // prep outputs live in
  short* WT  = attnw + 1048576;                         // not-yet-written attnw

  // WuT: own region past the 64 MB map if ws allows (prep fills it, no
  // wu_prep launch); else dead-Kw reuse after attn (extra launch).
  const bool extraWu = ws_size >= (64ull << 20) + (1ull << 20);
  short* WuT = extraWu ? (short*)((char*)d_ws + (64ull << 20)) : Kw;

  prep<<<dim3(extraWu ? 96 : 88), 256, 0, stream>>>(x, Wq, Wk, Wv, Wu, xbf, WT, WuT);
  qkv_proj<<<dim3(64, 8), 256, 0, stream>>>(xbf, WT, Qw, Kw, Vw);
  attn_kernel<<<dim3(1024), 256, 0, stream>>>(Qw, Kw, Vw, attnw);
  if (!extraWu) wu_prep<<<dim3(8), 256, 0, stream>>>(Wu, WuT);
  out_proj<<<dim3(512), 256, 0, stream>>>(attnw, WuT, bu, out);
}